// Round 12
// baseline (171.698 us; speedup 1.0000x reference)
//
#include <hip/hip_runtime.h>
#include <hip/hip_bf16.h>

// ---------------- problem constants ----------------
#define NG      19
#define HEIGHT  256
#define WIDTH   512
#define HW      (HEIGHT*WIDTH)        // 131072
#define BATCH   4
#define TH      8                     // tile rows
#define TW      128                   // tile cols
#define HALO_R  10
#define HALO_CU 66                    // u32 cols = 132 bf16 cols, origin tc0-2
#define CH_U32  (HALO_R*HALO_CU)      // 660
#define LDS_U32 (5*CH_U32)            // 3300 u32 = 13.2 KB (single copy)
#define WFRAG_SHORTS (NG*64*16)
#define BIAS_FLOATS  (NG*16)

typedef __attribute__((ext_vector_type(8))) short short8;
typedef __attribute__((ext_vector_type(4))) float f32x4;
typedef __attribute__((ext_vector_type(2))) float f32x2;
typedef __attribute__((ext_vector_type(4))) unsigned int u32x4;

static __device__ __forceinline__ unsigned int bfbits(float f) {
    return (unsigned int)__builtin_bit_cast(unsigned short, __float2bfloat16(f));
}
static __device__ __forceinline__ unsigned int pack2(float lo, float hi) {
    return bfbits(lo) | (bfbits(hi) << 16);
}
static __device__ __forceinline__ unsigned int fsh16(unsigned int hi, unsigned int lo) {
    return (unsigned int)((((unsigned long long)hi << 32) | lo) >> 16);  // v_alignbit
}

// K enumeration: k = m*4 + kc, m = (ic*3+kr) in 0..14, kc in 0..3.
// kc==3 and m==15 are zero-weight pad slots.
// A row = oc_perm = s*4 + gate -> D gives lane-local gates per (pixel,slab).
// exp2 scales folded: gates i,f,o scaled by -1.4427 (sigma(A)=1/(1+2^a)),
// gate g scaled by -2.8854 (tanh(A)=(1-2^a)/(1+2^a)).
__global__ void wxform_kernel(const float* __restrict__ W,
                              const float* __restrict__ b,
                              short* __restrict__ wdst,
                              float* __restrict__ bdst) {
    int i = blockIdx.x * 256 + threadIdx.x;
    if (i < WFRAG_SHORTS) {
        int g   = i / 1024;
        int r   = i & 1023;
        int l   = r >> 4;          // lane 0..63
        int j   = r & 15;          // element 0..15
        int q   = l >> 4;
        int row = l & 15;          // oc_perm = s*4 + gate
        int s    = row >> 2;
        int gate = row & 3;
        int half = j >> 3;
        int jj   = j & 7;
        int m  = 8*half + 2*q + (jj >> 2);   // (ic,kr) combo index
        int kc = jj & 3;
        float wv = 0.0f;
        if (m <= 14 && kc < 3) {
            int ic = m / 3, kr = m % 3;
            int oc = g*16 + gate*4 + s;
            float scale = (gate == 3) ? -2.88539008f : -1.44269504f;
            wv = scale * W[((oc*5 + ic)*3 + kr)*3 + kc];
        }
        wdst[i] = (short)__builtin_bit_cast(unsigned short, __float2bfloat16(wv));
    } else if (i < WFRAG_SHORTS + BIAS_FLOATS) {
        int idx = i - WFRAG_SHORTS;
        int g = idx >> 4;
        int r = idx & 15;
        int s = r >> 2, gate = r & 3;
        float scale = (gate == 3) ? -2.88539008f : -1.44269504f;
        bdst[idx] = scale * b[g*16 + gate*4 + s];   // [g][s][gate]
    }
}

// Single-copy LDS of the 10 x 132 halo (5 channels) as packed bf16 pairs.
// Window extraction via 16-bit funnel shifts (VALU has headroom).
__launch_bounds__(256, 8)
__global__ void convlstm_mfma(const float* __restrict__ x,
                              const float* __restrict__ h,
                              const float* __restrict__ c,
                              const short* __restrict__ wfrag,
                              const float* __restrict__ biasp,
                              float* __restrict__ out) {
    __shared__ unsigned int lds0[LDS_U32];

    const int t     = threadIdx.x;
    const int bid   = blockIdx.x;
    const int plane = bid >> 7;            // (b*19+g)
    const int tile  = bid & 127;
    const int tr0   = (tile >> 2) * TH;    // 32 row bands
    const int tc0   = (tile & 3)  * TW;    // 4 col tiles
    const int g     = plane % NG;

    const int w  = t >> 6;     // wave: owns tile rows 2w, 2w+1
    const int l  = t & 63;
    const int q  = l >> 4;     // slab
    const int li = l & 15;     // B column

    const int NC_OFF   = BATCH * NG * 4 * HW;   // 39,845,888
    const int rowbase0 = (plane*4 + q)*HW + (tr0 + 2*w)*WIDTH + tc0 + 4*li;

    // all 4 c vectors in flight immediately (nontemporal read-once stream)
    f32x4 cp[4];
    #pragma unroll
    for (int rr = 0; rr < 2; ++rr)
        #pragma unroll
        for (int cc = 0; cc < 2; ++cc)
            cp[rr*2 + cc] = __builtin_nontemporal_load(
                reinterpret_cast<const f32x4*>(c + rowbase0 + rr*WIDTH + cc*64));

    // A fragments + bias (scales folded)
    const short8* ap = reinterpret_cast<const short8*>(wfrag + (g*64 + l)*16);
    const short8 a_lo = ap[0];
    const short8 a_hi = ap[1];
    const f32x4 bias4 = *reinterpret_cast<const f32x4*>(biasp + g*16 + q*4);

    // ---- staging: 13 slots/thread (7+6 batches), incremental (ch,r,j2) walk ----
    const float* xb = x + plane * HW;
    const float* hb = h + (plane * 4) * HW;
    const bool lt = (tc0 == 0), rt = (tc0 == 384);

    int r  = t / HALO_CU;          // 0..3
    int j2 = t - r * HALO_CU;      // 0..65
    int ch = 0;

    #pragma unroll
    for (int half = 0; half < 2; ++half) {
        const int NB = half ? 6 : 7;
        f32x2 pf[7]; int pidx[7]; bool vld[7];
        #pragma unroll
        for (int k2 = 0; k2 < 7; ++k2) {
            if (k2 >= NB) break;
            const int k = half ? (7 + k2) : k2;
            const int p = t + 256*k;
            const bool v = (k < 12) || (t < (LDS_U32 - 12*256));
            pidx[k2] = p;  vld[k2] = v;
            const int  gr  = tr0 + r - 1;
            const bool rok = v && ((unsigned)gr < HEIGHT);
            const bool pok = rok && !(lt && j2 == 0) && !(rt && j2 == 65);
            const float* bp = (ch == 0) ? xb : (hb + (ch - 1) * HW);
            const int off = gr*WIDTH + tc0 + 2*j2 - 2;
            f32x2 z; z[0] = 0.0f; z[1] = 0.0f;
            pf[k2] = pok ? *reinterpret_cast<const f32x2*>(bp + off) : z;
            // advance by +256 slots: 256 = 3*66 + 58
            j2 += 58; r += 3;
            if (j2 >= HALO_CU) { j2 -= HALO_CU; r += 1; }
            if (r  >= HALO_R)  { r  -= HALO_R;  ch += 1; }
        }
        #pragma unroll
        for (int k2 = 0; k2 < 7; ++k2) {
            if (k2 >= NB) break;
            if (vld[k2]) lds0[pidx[k2]] = pack2(pf[k2][0], pf[k2][1]);
        }
    }

    asm volatile("s_waitcnt lgkmcnt(0)" ::: "memory");
    __builtin_amdgcn_s_barrier();
    asm volatile("" ::: "memory");

    // ---- per-lane combo dword bases ----
    int cbase[4];
    #pragma unroll
    for (int i = 0; i < 4; ++i) {
        int m = (i < 2) ? (2*q + i) : (8 + 2*q + (i - 2));
        if (m > 14) m = 14;                      // m==15 pad: weight is 0
        cbase[i] = (m/3)*CH_U32 + (m%3)*HALO_CU + 2*li;
    }

    #pragma unroll
    for (int rr = 0; rr < 2; ++rr) {
        const int tr = 2*w + rr;
        #pragma unroll
        for (int cc = 0; cc < 2; ++cc) {
            const int dadd = tr*HALO_CU + cc*32;
            uint2 dv[4][2];
            #pragma unroll
            for (int i = 0; i < 4; ++i) {
                const int idx = cbase[i] + dadd;        // even -> 8B aligned
                dv[i][0] = *reinterpret_cast<const uint2*>(&lds0[idx]);      // ds_read_b64
                dv[i][1] = *reinterpret_cast<const uint2*>(&lds0[idx + 2]);  // ds_read_b64
            }
            float nh4[4], nc4[4];
            #pragma unroll
            for (int n = 0; n < 4; ++n) {
                // window bf16 cols (halo, origin tc0-2): cc*64+4li+n+1 .. +4
                u32x4 blo_u, bhi_u;
                #pragma unroll
                for (int i = 0; i < 4; ++i) {
                    const unsigned d0 = dv[i][0].x, d1 = dv[i][0].y;
                    const unsigned d2 = dv[i][1].x, d3 = dv[i][1].y;
                    unsigned w0, w1;
                    if (n == 0)      { w0 = fsh16(d1,d0); w1 = fsh16(d2,d1); }
                    else if (n == 1) { w0 = d1;           w1 = d2;           }
                    else if (n == 2) { w0 = fsh16(d2,d1); w1 = fsh16(d3,d2); }
                    else             { w0 = d2;           w1 = d3;           }
                    if (i < 2) { blo_u[2*i]     = w0; blo_u[2*i+1]     = w1; }
                    else       { bhi_u[2*(i-2)] = w0; bhi_u[2*(i-2)+1] = w1; }
                }
                const short8 blo = __builtin_bit_cast(short8, blo_u);
                const short8 bhi = __builtin_bit_cast(short8, bhi_u);

                f32x4 acc = bias4;
                acc = __builtin_amdgcn_mfma_f32_16x16x32_bf16(a_lo, blo, acc, 0, 0, 0);
                acc = __builtin_amdgcn_mfma_f32_16x16x32_bf16(a_hi, bhi, acc, 0, 0, 0);

                // fused-reciprocal LSTM epilogue: 5 exp2 + 2 rcp per pixel
                const float cv = cp[rr*2 + cc][n];
                const float u  = __builtin_amdgcn_exp2f(acc[0]);
                const float v  = __builtin_amdgcn_exp2f(acc[1]);
                const float wo = __builtin_amdgcn_exp2f(acc[2]);
                const float z  = __builtin_amdgcn_exp2f(acc[3]);
                const float pu = 1.0f + u,  pv = 1.0f + v;
                const float pw = 1.0f + wo, pz = 1.0f + z;
                const float puz = pu * pz;
                const float r1  = __builtin_amdgcn_rcpf(pv * puz);
                const float nc  = fmaf(cv, puz, (1.0f - z) * pv) * r1;
                const float tt2 = __builtin_amdgcn_exp2f(-2.88539008f * nc);
                const float r2  = __builtin_amdgcn_rcpf(pw * (1.0f + tt2));
                nc4[n] = nc;
                nh4[n] = (1.0f - tt2) * r2;
            }
            const int rowchan = rowbase0 + rr*WIDTH + cc*64;
            f32x4 nhv; nhv[0]=nh4[0]; nhv[1]=nh4[1]; nhv[2]=nh4[2]; nhv[3]=nh4[3];
            f32x4 ncv; ncv[0]=nc4[0]; ncv[1]=nc4[1]; ncv[2]=nc4[2]; ncv[3]=nc4[3];
            __builtin_nontemporal_store(nhv, reinterpret_cast<f32x4*>(out + rowchan));
            __builtin_nontemporal_store(ncv, reinterpret_cast<f32x4*>(out + NC_OFF + rowchan));
        }
    }
}

extern "C" void kernel_launch(void* const* d_in, const int* in_sizes, int n_in,
                              void* d_out, int out_size, void* d_ws, size_t ws_size,
                              hipStream_t stream) {
    (void)in_sizes; (void)n_in; (void)out_size; (void)ws_size;
    const float* x = (const float*)d_in[0];
    const float* h = (const float*)d_in[1];
    const float* c = (const float*)d_in[2];
    const float* W = (const float*)d_in[3];
    const float* b = (const float*)d_in[4];
    float* out = (float*)d_out;

    short* wdst = (short*)d_ws;                                         // 38,912 B
    float* bdst = (float*)((char*)d_ws + WFRAG_SHORTS * sizeof(short)); // +1,216 B

    hipLaunchKernelGGL(wxform_kernel,
                       dim3((WFRAG_SHORTS + BIAS_FLOATS + 255) / 256), dim3(256),
                       0, stream, W, b, wdst, bdst);
    hipLaunchKernelGGL(convlstm_mfma, dim3(BATCH * NG * 128), dim3(256),
                       0, stream, x, h, c, (const short*)wdst, bdst, out);
}

// Round 13
// 121.571 us; speedup vs baseline: 1.4123x; 1.4123x over previous
//
#include <hip/hip_runtime.h>
#include <hip/hip_bf16.h>

// ---------------- problem constants ----------------
#define NG      19
#define HEIGHT  256
#define WIDTH   512
#define HW      (HEIGHT*WIDTH)        // 131072
#define BATCH   4
#define TH      16                    // tile rows
#define TW      256                   // tile cols (1KB runs on c/out streams)
#define HALO_R  18
#define HALO_CU 130                   // u32 cols = 260 bf16 cols, origin tc0-2
#define CH_U32  (HALO_R*HALO_CU)      // 2340
#define LDS_U32 (5*CH_U32)            // 11700 u32 = 46.8 KB single copy
#define WFRAG_SHORTS (NG*64*16)
#define BIAS_FLOATS  (NG*16)

typedef __attribute__((ext_vector_type(8))) short short8;
typedef __attribute__((ext_vector_type(4))) float f32x4;
typedef __attribute__((ext_vector_type(2))) float f32x2;
typedef __attribute__((ext_vector_type(4))) unsigned int u32x4;

static __device__ __forceinline__ unsigned int bfbits(float f) {
    return (unsigned int)__builtin_bit_cast(unsigned short, __float2bfloat16(f));
}
static __device__ __forceinline__ unsigned int pack2(float lo, float hi) {
    return bfbits(lo) | (bfbits(hi) << 16);
}
static __device__ __forceinline__ unsigned int fsh16(unsigned int hi, unsigned int lo) {
    return (unsigned int)((((unsigned long long)hi << 32) | lo) >> 16);  // v_alignbit
}

// K enumeration: k = m*4 + kc, m = (ic*3+kr) in 0..14, kc in 0..3.
// kc==3 and m==15 are zero-weight pad slots.
// A row = oc_perm = s*4 + gate -> D gives lane-local gates per (pixel,slab).
// exp2 scales folded: i,f,o by -1.4427 (sigma(A)=1/(1+2^a)); g by -2.8854.
__global__ void wxform_kernel(const float* __restrict__ W,
                              const float* __restrict__ b,
                              short* __restrict__ wdst,
                              float* __restrict__ bdst) {
    int i = blockIdx.x * 256 + threadIdx.x;
    if (i < WFRAG_SHORTS) {
        int g   = i / 1024;
        int r   = i & 1023;
        int l   = r >> 4;          // lane 0..63
        int j   = r & 15;          // element 0..15
        int q   = l >> 4;
        int row = l & 15;          // oc_perm = s*4 + gate
        int s    = row >> 2;
        int gate = row & 3;
        int half = j >> 3;
        int jj   = j & 7;
        int m  = 8*half + 2*q + (jj >> 2);   // (ic,kr) combo index
        int kc = jj & 3;
        float wv = 0.0f;
        if (m <= 14 && kc < 3) {
            int ic = m / 3, kr = m % 3;
            int oc = g*16 + gate*4 + s;
            float scale = (gate == 3) ? -2.88539008f : -1.44269504f;
            wv = scale * W[((oc*5 + ic)*3 + kr)*3 + kc];
        }
        wdst[i] = (short)__builtin_bit_cast(unsigned short, __float2bfloat16(wv));
    } else if (i < WFRAG_SHORTS + BIAS_FLOATS) {
        int idx = i - WFRAG_SHORTS;
        int g = idx >> 4;
        int r = idx & 15;
        int s = r >> 2, gate = r & 3;
        float scale = (gate == 3) ? -2.88539008f : -1.44269504f;
        bdst[idx] = scale * b[g*16 + gate*4 + s];   // [g][s][gate]
    }
}

// 3 blocks/CU (LDS 46.8KB): 12 waves/CU
__launch_bounds__(256, 3)
__global__ void convlstm_mfma(const float* __restrict__ x,
                              const float* __restrict__ h,
                              const float* __restrict__ c,
                              const short* __restrict__ wfrag,
                              const float* __restrict__ biasp,
                              float* __restrict__ out) {
    __shared__ unsigned int lds0[LDS_U32];

    const int t     = threadIdx.x;
    const int bid   = blockIdx.x;
    const int plane = bid >> 5;            // (b*19+g)
    const int tile  = bid & 31;
    const int tr0   = (tile >> 1) * TH;    // 16 row bands
    const int tc0   = (tile & 1)  * TW;    // 2 col tiles
    const int g     = plane % NG;

    const int w  = t >> 6;     // wave: owns tile rows w*4..w*4+3
    const int l  = t & 63;
    const int q  = l >> 4;     // slab
    const int li = l & 15;

    const int NC_OFF   = BATCH * NG * 4 * HW;   // 39,845,888
    const int rowbase0 = (plane*4 + q)*HW + (tr0 + w*4)*WIDTH + tc0 + 4*li;

    // A fragments + bias (scales folded)
    const short8* ap = reinterpret_cast<const short8*>(wfrag + (g*64 + l)*16);
    const short8 a_lo = ap[0];
    const short8 a_hi = ap[1];
    const f32x4 bias4 = *reinterpret_cast<const f32x4*>(biasp + g*16 + q*4);

    // ---- staging: 46 slots/thread, 6 batches of 8, incremental (ch,r,j2) walk ----
    const float* xb = x + plane * HW;
    const float* hb = h + (plane * 4) * HW;
    const bool lt = (tc0 == 0), rt = (tc0 == 256);

    int r  = t / HALO_CU;          // 0..1
    int j2 = t - r * HALO_CU;      // 0..129
    int ch = 0;

    #pragma unroll
    for (int bt = 0; bt < 6; ++bt) {
        f32x2 pf[8]; bool vld[8];
        #pragma unroll
        for (int k2 = 0; k2 < 8; ++k2) {
            const int k = bt*8 + k2;
            const bool v = (k < 45) || (k == 45 && t < (LDS_U32 - 45*256));
            vld[k2] = v;
            const int  gr  = tr0 + r - 1;
            const bool rok = v && ((unsigned)gr < HEIGHT);
            const bool pok = rok && !(lt && j2 == 0) && !(rt && j2 == HALO_CU-1);
            const float* bp = (ch == 0) ? xb : (hb + (ch - 1) * HW);
            const int off = gr*WIDTH + tc0 + 2*j2 - 2;
            f32x2 z; z[0] = 0.0f; z[1] = 0.0f;
            pf[k2] = pok ? *reinterpret_cast<const f32x2*>(bp + off) : z;
            // advance by +256 slots: 256 = 1*130 + 126
            r += 1; j2 += 126;
            if (j2 >= HALO_CU) { j2 -= HALO_CU; r += 1; }
            if (r  >= HALO_R)  { r  -= HALO_R;  ch += 1; }
        }
        #pragma unroll
        for (int k2 = 0; k2 < 8; ++k2) {
            if (vld[k2]) lds0[t + 256*(bt*8 + k2)] = pack2(pf[k2][0], pf[k2][1]);
        }
    }

    // c for tr4=0 in flight before the barrier (nontemporal read-once)
    f32x4 cp0[4], cp1[4];
    #pragma unroll
    for (int cc = 0; cc < 4; ++cc)
        cp0[cc] = __builtin_nontemporal_load(
            reinterpret_cast<const f32x4*>(c + rowbase0 + cc*64));

    asm volatile("s_waitcnt lgkmcnt(0)" ::: "memory");
    __builtin_amdgcn_s_barrier();
    asm volatile("" ::: "memory");

    // ---- per-lane combo dword bases ----
    int cbase[4];
    #pragma unroll
    for (int i = 0; i < 4; ++i) {
        int m = (i < 2) ? (2*q + i) : (8 + 2*q + (i - 2));
        if (m > 14) m = 14;                      // m==15 pad: weight is 0
        cbase[i] = (m/3)*CH_U32 + (m%3)*HALO_CU + 2*li;
    }

    #pragma unroll
    for (int tr4 = 0; tr4 < 4; ++tr4) {
        // prefetch next row's c under this row's compute (static ping-pong)
        f32x4* cpc = (tr4 & 1) ? cp1 : cp0;
        f32x4* cpn = (tr4 & 1) ? cp0 : cp1;
        if (tr4 < 3) {
            #pragma unroll
            for (int cc = 0; cc < 4; ++cc)
                cpn[cc] = __builtin_nontemporal_load(
                    reinterpret_cast<const f32x4*>(c + rowbase0 + (tr4+1)*WIDTH + cc*64));
        }

        const int tr = w*4 + tr4;
        #pragma unroll
        for (int cc = 0; cc < 4; ++cc) {
            const int dadd = tr*HALO_CU + cc*32;
            uint2 dv[4][2];
            #pragma unroll
            for (int i = 0; i < 4; ++i) {
                const int idx = cbase[i] + dadd;        // even -> 8B aligned
                dv[i][0] = *reinterpret_cast<const uint2*>(&lds0[idx]);      // ds_read_b64
                dv[i][1] = *reinterpret_cast<const uint2*>(&lds0[idx + 2]);  // ds_read_b64
            }
            float nh4[4], nc4[4];
            #pragma unroll
            for (int n = 0; n < 4; ++n) {
                // window bf16 halo cols: cc*64 + 4li + n+1 .. n+4
                u32x4 blo_u, bhi_u;
                #pragma unroll
                for (int i = 0; i < 4; ++i) {
                    const unsigned d0 = dv[i][0].x, d1 = dv[i][0].y;
                    const unsigned d2 = dv[i][1].x, d3 = dv[i][1].y;
                    unsigned w0, w1;
                    if (n == 0)      { w0 = fsh16(d1,d0); w1 = fsh16(d2,d1); }
                    else if (n == 1) { w0 = d1;           w1 = d2;           }
                    else if (n == 2) { w0 = fsh16(d2,d1); w1 = fsh16(d3,d2); }
                    else             { w0 = d2;           w1 = d3;           }
                    if (i < 2) { blo_u[2*i]     = w0; blo_u[2*i+1]     = w1; }
                    else       { bhi_u[2*(i-2)] = w0; bhi_u[2*(i-2)+1] = w1; }
                }
                const short8 blo = __builtin_bit_cast(short8, blo_u);
                const short8 bhi = __builtin_bit_cast(short8, bhi_u);

                f32x4 acc = bias4;
                acc = __builtin_amdgcn_mfma_f32_16x16x32_bf16(a_lo, blo, acc, 0, 0, 0);
                acc = __builtin_amdgcn_mfma_f32_16x16x32_bf16(a_hi, bhi, acc, 0, 0, 0);

                // fused-reciprocal LSTM epilogue: 5 exp2 + 2 rcp per pixel
                const float cv = cpc[cc][n];
                const float u  = __builtin_amdgcn_exp2f(acc[0]);
                const float v  = __builtin_amdgcn_exp2f(acc[1]);
                const float wo = __builtin_amdgcn_exp2f(acc[2]);
                const float z  = __builtin_amdgcn_exp2f(acc[3]);
                const float pu = 1.0f + u,  pv = 1.0f + v;
                const float pw = 1.0f + wo, pz = 1.0f + z;
                const float puz = pu * pz;
                const float r1  = __builtin_amdgcn_rcpf(pv * puz);
                const float nc  = fmaf(cv, puz, (1.0f - z) * pv) * r1;
                const float tt2 = __builtin_amdgcn_exp2f(-2.88539008f * nc);
                const float r2  = __builtin_amdgcn_rcpf(pw * (1.0f + tt2));
                nc4[n] = nc;
                nh4[n] = (1.0f - tt2) * r2;
            }
            const int rowchan = rowbase0 + tr4*WIDTH + cc*64;
            f32x4 nhv; nhv[0]=nh4[0]; nhv[1]=nh4[1]; nhv[2]=nh4[2]; nhv[3]=nh4[3];
            f32x4 ncv; ncv[0]=nc4[0]; ncv[1]=nc4[1]; ncv[2]=nc4[2]; ncv[3]=nc4[3];
            __builtin_nontemporal_store(nhv, reinterpret_cast<f32x4*>(out + rowchan));
            __builtin_nontemporal_store(ncv, reinterpret_cast<f32x4*>(out + NC_OFF + rowchan));
        }
    }
}

extern "C" void kernel_launch(void* const* d_in, const int* in_sizes, int n_in,
                              void* d_out, int out_size, void* d_ws, size_t ws_size,
                              hipStream_t stream) {
    (void)in_sizes; (void)n_in; (void)out_size; (void)ws_size;
    const float* x = (const float*)d_in[0];
    const float* h = (const float*)d_in[1];
    const float* c = (const float*)d_in[2];
    const float* W = (const float*)d_in[3];
    const float* b = (const float*)d_in[4];
    float* out = (float*)d_out;

    short* wdst = (short*)d_ws;                                         // 38,912 B
    float* bdst = (float*)((char*)d_ws + WFRAG_SHORTS * sizeof(short)); // +1,216 B

    hipLaunchKernelGGL(wxform_kernel,
                       dim3((WFRAG_SHORTS + BIAS_FLOATS + 255) / 256), dim3(256),
                       0, stream, W, b, wdst, bdst);
    hipLaunchKernelGGL(convlstm_mfma, dim3(BATCH * NG * 32), dim3(256),
                       0, stream, x, h, c, (const short*)wdst, bdst, out);
}

// Round 14
// 119.666 us; speedup vs baseline: 1.4348x; 1.0159x over previous
//
#include <hip/hip_runtime.h>
#include <hip/hip_bf16.h>

// ---------------- problem constants ----------------
#define NG      19
#define HEIGHT  256
#define WIDTH   512
#define HW      (HEIGHT*WIDTH)        // 131072
#define BATCH   4
#define TH      8                     // tile rows; full-width tiles (TW=512)
#define NBANDS  32                    // 256/8 row bands
#define HALO_R  10
#define HALO_CU 260                   // u32 cols; slot s holds global cols (2s-4, 2s-3)
#define CH_U32  (HALO_R*HALO_CU)      // 2600
#define LDS_U32 (5*CH_U32)            // 13000 u32 = 52 KB
#define GTOT    6500                  // f32x4 staging groups (5 ch * 10 rows * 130)
#define WFRAG_SHORTS (NG*64*16)
#define BIAS_FLOATS  (NG*16)

typedef __attribute__((ext_vector_type(8))) short short8;
typedef __attribute__((ext_vector_type(4))) float f32x4;
typedef __attribute__((ext_vector_type(4))) unsigned int u32x4;

static __device__ __forceinline__ unsigned int bfbits(float f) {
    return (unsigned int)__builtin_bit_cast(unsigned short, __float2bfloat16(f));
}
static __device__ __forceinline__ unsigned int pack2(float lo, float hi) {
    return bfbits(lo) | (bfbits(hi) << 16);
}
static __device__ __forceinline__ unsigned int fsh16(unsigned int hi, unsigned int lo) {
    return (unsigned int)((((unsigned long long)hi << 32) | lo) >> 16);  // v_alignbit
}

// K enumeration: k = m*4 + kc, m = (ic*3+kr) in 0..14, kc in 0..3.
// kc==3 and m==15 are zero-weight pad slots.
// A row = oc_perm = s*4 + gate -> D gives lane-local gates per (pixel,slab).
// exp2 scales folded: i,f,o by -1.4427 (sigma(A)=1/(1+2^a)); g by -2.8854.
__global__ void wxform_kernel(const float* __restrict__ W,
                              const float* __restrict__ b,
                              short* __restrict__ wdst,
                              float* __restrict__ bdst) {
    int i = blockIdx.x * 256 + threadIdx.x;
    if (i < WFRAG_SHORTS) {
        int g   = i / 1024;
        int r   = i & 1023;
        int l   = r >> 4;          // lane 0..63
        int j   = r & 15;          // element 0..15
        int q   = l >> 4;
        int row = l & 15;          // oc_perm = s*4 + gate
        int s    = row >> 2;
        int gate = row & 3;
        int half = j >> 3;
        int jj   = j & 7;
        int m  = 8*half + 2*q + (jj >> 2);   // (ic,kr) combo index
        int kc = jj & 3;
        float wv = 0.0f;
        if (m <= 14 && kc < 3) {
            int ic = m / 3, kr = m % 3;
            int oc = g*16 + gate*4 + s;
            float scale = (gate == 3) ? -2.88539008f : -1.44269504f;
            wv = scale * W[((oc*5 + ic)*3 + kr)*3 + kc];
        }
        wdst[i] = (short)__builtin_bit_cast(unsigned short, __float2bfloat16(wv));
    } else if (i < WFRAG_SHORTS + BIAS_FLOATS) {
        int idx = i - WFRAG_SHORTS;
        int g = idx >> 4;
        int r = idx & 15;
        int s = r >> 2, gate = r & 3;
        float scale = (gate == 3) ? -2.88539008f : -1.44269504f;
        bdst[idx] = scale * b[g*16 + gate*4 + s];   // [g][s][gate]
    }
}

// Full-width band: block = (plane, 8-row band). c/out streams are 2KB/row,
// 16KB-contiguous per plane per block. Staging = aligned f32x4 full rows.
__launch_bounds__(256, 3)
__global__ void convlstm_mfma(const float* __restrict__ x,
                              const float* __restrict__ h,
                              const float* __restrict__ c,
                              const short* __restrict__ wfrag,
                              const float* __restrict__ biasp,
                              float* __restrict__ out) {
    __shared__ unsigned int lds0[LDS_U32];

    const int t   = threadIdx.x;
    // chunked XCD swizzle (bijective: 2432 = 8 * 304): consecutive logical
    // bands land on the same XCD -> shared halo rows hit that XCD's L2.
    const int bid = ((blockIdx.x & 7) * 304) + (blockIdx.x >> 3);
    const int plane = bid >> 5;            // (b*19+g)
    const int tr0   = (bid & 31) * TH;     // row band
    const int g     = plane % NG;

    const int w  = t >> 6;     // wave: owns tile rows 2w, 2w+1
    const int l  = t & 63;
    const int q  = l >> 4;     // slab
    const int li = l & 15;

    const int NC_OFF   = BATCH * NG * 4 * HW;   // 39,845,888
    const int rowbase0 = (plane*4 + q)*HW + (tr0 + 2*w)*WIDTH + 4*li;

    // A fragments + bias (scales folded)
    const short8* ap = reinterpret_cast<const short8*>(wfrag + (g*64 + l)*16);
    const short8 a_lo = ap[0];
    const short8 a_hi = ap[1];
    const f32x4 bias4 = *reinterpret_cast<const f32x4*>(biasp + g*16 + q*4);

    // ---- staging: 26 aligned f32x4 groups/thread, 2 batches of 13 ----
    // group p: ch = p/1300, r = (p%1300)/130, m = p%130; floats at
    // gr*WIDTH + 4m - 4 (16B aligned); m==0 / m==129 are whole-group zero pads.
    const float* xb = x + plane * HW;
    const float* hb = h + (plane * 4) * HW;

    int r  = t / 130;
    int m  = t - r * 130;
    int ch = 0;

    #pragma unroll
    for (int half = 0; half < 2; ++half) {
        f32x4 pf[13]; int pidx[13]; bool vld[13];
        #pragma unroll
        for (int k2 = 0; k2 < 13; ++k2) {
            const int k = half*13 + k2;
            const int p = t + 256*k;
            const bool v = (k < 25) || (t < (GTOT - 25*256));
            pidx[k2] = p;  vld[k2] = v;
            const int  gr  = tr0 + r - 1;
            const bool rok = v && ((unsigned)gr < HEIGHT);
            const bool pok = rok && (m != 0) && (m != 129);
            const int  chc = (ch < 4) ? ch : 4;
            const float* bp = (chc == 0) ? xb : (hb + (chc - 1) * HW);
            const int off = gr*WIDTH + 4*m - 4;
            f32x4 z; z[0]=0.0f; z[1]=0.0f; z[2]=0.0f; z[3]=0.0f;
            pf[k2] = pok ? *reinterpret_cast<const f32x4*>(bp + off) : z;
            // advance p by 256 groups: 256 = 2*130 - 4
            r += 1; m += 126;
            if (m >= 130) { m -= 130; r += 1; }
            if (r >= 10)  { r -= 10;  ch += 1; }
        }
        #pragma unroll
        for (int k2 = 0; k2 < 13; ++k2) {
            if (vld[k2]) {
                lds0[2*pidx[k2]]     = pack2(pf[k2][0], pf[k2][1]);
                lds0[2*pidx[k2] + 1] = pack2(pf[k2][2], pf[k2][3]);
            }
        }
    }

    // c for row 0 in flight before the barrier (nontemporal read-once)
    f32x4 cpA[8], cpB[8];
    #pragma unroll
    for (int cc = 0; cc < 8; ++cc)
        cpA[cc] = __builtin_nontemporal_load(
            reinterpret_cast<const f32x4*>(c + rowbase0 + cc*64));

    asm volatile("s_waitcnt lgkmcnt(0)" ::: "memory");
    __builtin_amdgcn_s_barrier();
    asm volatile("" ::: "memory");

    // ---- per-lane combo dword bases ----
    int cbase[4];
    #pragma unroll
    for (int i = 0; i < 4; ++i) {
        int mi = (i < 2) ? (2*q + i) : (8 + 2*q + (i - 2));
        if (mi > 14) mi = 14;                    // m==15 pad: weight is 0
        cbase[i] = (mi/3)*CH_U32 + (mi%3)*HALO_CU + 2*li;
    }

    #pragma unroll
    for (int rr = 0; rr < 2; ++rr) {
        const f32x4* cpc = rr ? cpB : cpA;
        if (rr == 0) {
            // prefetch row 1's c under row 0's compute
            #pragma unroll
            for (int cc = 0; cc < 8; ++cc)
                cpB[cc] = __builtin_nontemporal_load(
                    reinterpret_cast<const f32x4*>(c + rowbase0 + WIDTH + cc*64));
        }
        const int tr = 2*w + rr;

        #pragma unroll
        for (int cc = 0; cc < 8; ++cc) {
            // window slots: Di+1..Di+4 per combo (ds_read2_b32 pairs)
            unsigned Lw[4][4];
            #pragma unroll
            for (int i = 0; i < 4; ++i) {
                const int D = cbase[i] + tr*HALO_CU + cc*32;
                Lw[i][0] = lds0[D+1];
                Lw[i][1] = lds0[D+2];
                Lw[i][2] = lds0[D+3];
                Lw[i][3] = lds0[D+4];
            }
            float nh4[4], nc4[4];
            #pragma unroll
            for (int n = 0; n < 4; ++n) {
                u32x4 blo_u, bhi_u;
                #pragma unroll
                for (int i = 0; i < 4; ++i) {
                    unsigned w0, w1;
                    if (n == 0)      { w0 = fsh16(Lw[i][1],Lw[i][0]); w1 = fsh16(Lw[i][2],Lw[i][1]); }
                    else if (n == 1) { w0 = Lw[i][1];                 w1 = Lw[i][2];                 }
                    else if (n == 2) { w0 = fsh16(Lw[i][2],Lw[i][1]); w1 = fsh16(Lw[i][3],Lw[i][2]); }
                    else             { w0 = Lw[i][2];                 w1 = Lw[i][3];                 }
                    if (i < 2) { blo_u[2*i]     = w0; blo_u[2*i+1]     = w1; }
                    else       { bhi_u[2*(i-2)] = w0; bhi_u[2*(i-2)+1] = w1; }
                }
                const short8 blo = __builtin_bit_cast(short8, blo_u);
                const short8 bhi = __builtin_bit_cast(short8, bhi_u);

                f32x4 acc = bias4;
                acc = __builtin_amdgcn_mfma_f32_16x16x32_bf16(a_lo, blo, acc, 0, 0, 0);
                acc = __builtin_amdgcn_mfma_f32_16x16x32_bf16(a_hi, bhi, acc, 0, 0, 0);

                // fused-reciprocal LSTM epilogue: 5 exp2 + 2 rcp per pixel
                const float cv = cpc[cc][n];
                const float u  = __builtin_amdgcn_exp2f(acc[0]);
                const float v  = __builtin_amdgcn_exp2f(acc[1]);
                const float wo = __builtin_amdgcn_exp2f(acc[2]);
                const float z  = __builtin_amdgcn_exp2f(acc[3]);
                const float pu = 1.0f + u,  pv = 1.0f + v;
                const float pw = 1.0f + wo, pz = 1.0f + z;
                const float puz = pu * pz;
                const float r1  = __builtin_amdgcn_rcpf(pv * puz);
                const float nc  = fmaf(cv, puz, (1.0f - z) * pv) * r1;
                const float tt2 = __builtin_amdgcn_exp2f(-2.88539008f * nc);
                const float r2  = __builtin_amdgcn_rcpf(pw * (1.0f + tt2));
                nc4[n] = nc;
                nh4[n] = (1.0f - tt2) * r2;
            }
            const int rowchan = rowbase0 + rr*WIDTH + cc*64;
            f32x4 nhv; nhv[0]=nh4[0]; nhv[1]=nh4[1]; nhv[2]=nh4[2]; nhv[3]=nh4[3];
            f32x4 ncv; ncv[0]=nc4[0]; ncv[1]=nc4[1]; ncv[2]=nc4[2]; ncv[3]=nc4[3];
            __builtin_nontemporal_store(nhv, reinterpret_cast<f32x4*>(out + rowchan));
            __builtin_nontemporal_store(ncv, reinterpret_cast<f32x4*>(out + NC_OFF + rowchan));
        }
    }
}

extern "C" void kernel_launch(void* const* d_in, const int* in_sizes, int n_in,
                              void* d_out, int out_size, void* d_ws, size_t ws_size,
                              hipStream_t stream) {
    (void)in_sizes; (void)n_in; (void)out_size; (void)ws_size;
    const float* x = (const float*)d_in[0];
    const float* h = (const float*)d_in[1];
    const float* c = (const float*)d_in[2];
    const float* W = (const float*)d_in[3];
    const float* b = (const float*)d_in[4];
    float* out = (float*)d_out;

    short* wdst = (short*)d_ws;                                         // 38,912 B
    float* bdst = (float*)((char*)d_ws + WFRAG_SHORTS * sizeof(short)); // +1,216 B

    hipLaunchKernelGGL(wxform_kernel,
                       dim3((WFRAG_SHORTS + BIAS_FLOATS + 255) / 256), dim3(256),
                       0, stream, W, b, wdst, bdst);
    hipLaunchKernelGGL(convlstm_mfma, dim3(BATCH * NG * NBANDS), dim3(256),
                       0, stream, x, h, c, (const short*)wdst, bdst, out);
}